// Round 7
// baseline (38.170 us; speedup 1.0000x reference)
//
#include <hip/hip_runtime.h>
#include <math.h>

#define NJ 24
#define NV 6890
#define NB 128

// Ancestor chains (closest ancestor first), -1 padded. Max depth 8.
__constant__ int d_anc[NJ][8] = {
  {-1,-1,-1,-1,-1,-1,-1,-1},
  { 0,-1,-1,-1,-1,-1,-1,-1},
  { 0,-1,-1,-1,-1,-1,-1,-1},
  { 0,-1,-1,-1,-1,-1,-1,-1},
  { 1, 0,-1,-1,-1,-1,-1,-1},
  { 2, 0,-1,-1,-1,-1,-1,-1},
  { 3, 0,-1,-1,-1,-1,-1,-1},
  { 4, 1, 0,-1,-1,-1,-1,-1},
  { 5, 2, 0,-1,-1,-1,-1,-1},
  { 6, 3, 0,-1,-1,-1,-1,-1},
  { 7, 4, 1, 0,-1,-1,-1,-1},
  { 8, 5, 2, 0,-1,-1,-1,-1},
  { 9, 6, 3, 0,-1,-1,-1,-1},
  { 9, 6, 3, 0,-1,-1,-1,-1},
  { 9, 6, 3, 0,-1,-1,-1,-1},
  {12, 9, 6, 3, 0,-1,-1,-1},
  {13, 9, 6, 3, 0,-1,-1,-1},
  {14, 9, 6, 3, 0,-1,-1,-1},
  {16,13, 9, 6, 3, 0,-1,-1},
  {17,14, 9, 6, 3, 0,-1,-1},
  {18,16,13, 9, 6, 3, 0,-1},
  {19,17,14, 9, 6, 3, 0,-1},
  {20,18,16,13, 9, 6, 3, 0},
  {21,19,17,14, 9, 6, 3, 0}
};
__constant__ int d_par[NJ] = {-1,0,0,0,1,2,3,4,5,6,7,8,9,9,9,12,13,14,16,17,18,19,20,21};

// Kernel 1: per-batch Rodrigues + parallel ancestor-path chain + J-correction.
// Output layout UNTRANSPOSED: Gc[b][m][12] (3x4 row-major per joint), so a
// 48-float chunk = 4 joints and pairs (j, j+1) within a joint are adjacent.
__global__ __launch_bounds__(64) void chain_kernel(const float* __restrict__ J,
                                                   const float* __restrict__ pose,
                                                   float* __restrict__ Gc) {
    int b = blockIdx.x;
    int tid = threadIdx.x;
    __shared__ float A[NJ][12];   // local [R|t] per joint

    if (tid < NJ) {
        int i = tid;
        const float* p = pose + ((size_t)b * NJ + i) * 3;
        float rx = p[0], ry = p[1], rz = p[2];
        float ex = rx + 1e-8f, ey = ry + 1e-8f, ez = rz + 1e-8f;
        float theta = sqrtf(ex * ex + ey * ey + ez * ez);
        float inv = 1.0f / theta;
        float hx = rx * inv, hy = ry * inv, hz = rz * inv;
        float c = cosf(theta * (float)M_PI);
        float s = sinf(theta);
        float oc = 1.0f - c;
        const float* jp = J + ((size_t)b * NJ + i) * 3;
        int par = d_par[i];
        float tx, ty, tz;
        if (par < 0) {
            tx = jp[0]; ty = jp[1]; tz = jp[2];
        } else {
            const float* jq = J + ((size_t)b * NJ + par) * 3;
            tx = jp[0] - jq[0]; ty = jp[1] - jq[1]; tz = jp[2] - jq[2];
        }
        A[i][0]  = c + oc * hx * hx;
        A[i][1]  = oc * hx * hy - s * hz;
        A[i][2]  = oc * hx * hz + s * hy;
        A[i][3]  = tx;
        A[i][4]  = oc * hy * hx + s * hz;
        A[i][5]  = c + oc * hy * hy;
        A[i][6]  = oc * hy * hz - s * hx;
        A[i][7]  = ty;
        A[i][8]  = oc * hz * hx - s * hy;
        A[i][9]  = oc * hz * hy + s * hx;
        A[i][10] = c + oc * hz * hz;
        A[i][11] = tz;
    }
    __syncthreads();

    if (tid < NJ) {
        int i = tid;
        float M[12];
        #pragma unroll
        for (int j = 0; j < 12; j++) M[j] = A[i][j];

        for (int k = 0; k < 8; k++) {
            int p = d_anc[i][k];
            if (p < 0) break;
            float P[12];
            #pragma unroll
            for (int j = 0; j < 12; j++) P[j] = A[p][j];
            float N[12];
            #pragma unroll
            for (int r = 0; r < 3; r++) {
                float p0 = P[r*4+0], p1 = P[r*4+1], p2 = P[r*4+2], p3 = P[r*4+3];
                N[r*4+0] = p0 * M[0] + p1 * M[4] + p2 * M[8];
                N[r*4+1] = p0 * M[1] + p1 * M[5] + p2 * M[9];
                N[r*4+2] = p0 * M[2] + p1 * M[6] + p2 * M[10];
                N[r*4+3] = p0 * M[3] + p1 * M[7] + p2 * M[11] + p3;
            }
            #pragma unroll
            for (int j = 0; j < 12; j++) M[j] = N[j];
        }

        const float* jp = J + ((size_t)b * NJ + i) * 3;
        float jx = jp[0], jy = jp[1], jz = jp[2];
        float* o = Gc + ((size_t)b * NJ + i) * 12;
        #pragma unroll
        for (int r = 0; r < 3; r++) {
            float g0 = M[r*4+0], g1 = M[r*4+1], g2 = M[r*4+2], g3 = M[r*4+3];
            float corr = g0 * jx + g1 * jy + g2 * jz;
            o[r*4+0] = g0;
            o[r*4+1] = g1;
            o[r*4+2] = g2;
            o[r*4+3] = g3 - corr;
        }
    }
}

typedef __attribute__((ext_vector_type(16))) float fx16;
typedef __attribute__((ext_vector_type(2)))  float f2;

__device__ __forceinline__ f2 mkf2(float a, float b) { f2 r; r.x = a; r.y = b; return r; }

// e is a compile-time constant after unrolling; &15 keeps dead arms in range.
#define GPAIR(e) ((e) < 16 ? mkf2(gA[(e) & 15], gA[((e) + 1) & 15]) \
                : (e) < 32 ? mkf2(gB[((e) - 16) & 15], gB[((e) - 15) & 15]) \
                           : mkf2(gC[((e) - 32) & 15], gC[((e) - 31) & 15]))

// Kernel 2: per-vertex skinning, 2 vertices/thread, SMEM-sourced Gc.
// Untransposed Gc layout: chunk c = joints 4c..4c+3; only one float4 of W
// per vertex is needed per chunk (pipelined one ahead), so VGPR stays low
// while each wave's SMEM-wait stalls amortize over 2 vertices of work.
// pk_fma packs element pairs (j, j+1): T2[e].x/.y are distinct outputs,
// no final cross-fold needed.
__global__ __launch_bounds__(256) void lbs_kernel(const float* __restrict__ V,
                                                  const float* __restrict__ W,
                                                  const float* __restrict__ Gc,
                                                  float* __restrict__ out) {
    const int b = blockIdx.y;
    const int tid = threadIdx.x;
    const int n0 = blockIdx.x * 512 + tid;
    if (n0 >= NV) return;
    const int n1 = n0 + 256;
    const bool has1 = (n1 < NV);
    const int n1c = has1 ? n1 : n0;   // clamped; result discarded if !has1

    const float* gb = Gc + (size_t)b * 288;
    const float4* __restrict__ wp0 = (const float4*)(W + ((size_t)b * NV + n0) * 24);
    const float4* __restrict__ wp1 = (const float4*)(W + ((size_t)b * NV + n1c) * 24);

    // Hoist V loads to overlap with the blend loop.
    const float* vp0 = V + ((size_t)b * NV + n0) * 3;
    const float* vp1 = V + ((size_t)b * NV + n1c) * 3;
    float v0x = vp0[0], v0y = vp0[1], v0z = vp0[2];
    float v1x = vp1[0], v1y = vp1[1], v1z = vp1[2];

    f2 Ta[6], Tb[6];
    #pragma unroll
    for (int j = 0; j < 6; j++) { Ta[j] = mkf2(0.f, 0.f); Tb[j] = mkf2(0.f, 0.f); }

    float4 wa = wp0[0];
    float4 wb = wp1[0];

    #pragma unroll
    for (int c = 0; c < 6; c++) {
        // 4 joints (48 floats) of Gc[b] into SGPRs; wait inside the asm so
        // every consumer of gA/gB/gC is ordered after the data arrives.
        fx16 gA, gB, gC;
        const float* p = gb + c * 48;
        asm volatile("s_load_dwordx16 %0, %3, 0x0\n\t"
                     "s_load_dwordx16 %1, %3, 0x40\n\t"
                     "s_load_dwordx16 %2, %3, 0x80\n\t"
                     "s_waitcnt lgkmcnt(0)"
                     : "=&s"(gA), "=&s"(gB), "=&s"(gC)
                     : "s"(p));

        float4 wac = wa, wbc = wb;
        if (c < 5) { wa = wp0[c + 1]; wb = wp1[c + 1]; }  // prefetch next chunk

        const float wav[4] = {wac.x, wac.y, wac.z, wac.w};
        const float wbv[4] = {wbc.x, wbc.y, wbc.z, wbc.w};
        #pragma unroll
        for (int q = 0; q < 4; q++) {
            f2 wwa = mkf2(wav[q], wav[q]);
            f2 wwb = mkf2(wbv[q], wbv[q]);
            #pragma unroll
            for (int e2 = 0; e2 < 6; e2++) {
                f2 gp = GPAIR(q * 12 + 2 * e2);
                asm("v_pk_fma_f32 %0, %1, %2, %0" : "+v"(Ta[e2]) : "v"(wwa), "s"(gp));
                asm("v_pk_fma_f32 %0, %1, %2, %0" : "+v"(Tb[e2]) : "v"(wwb), "s"(gp));
            }
        }
    }

    {
        float* op = out + ((size_t)b * NV + n0) * 3;
        op[0] = Ta[0].x * v0x + Ta[0].y * v0y + Ta[1].x * v0z + Ta[1].y;
        op[1] = Ta[2].x * v0x + Ta[2].y * v0y + Ta[3].x * v0z + Ta[3].y;
        op[2] = Ta[4].x * v0x + Ta[4].y * v0y + Ta[5].x * v0z + Ta[5].y;
    }
    if (has1) {
        float* op = out + ((size_t)b * NV + n1) * 3;
        op[0] = Tb[0].x * v1x + Tb[0].y * v1y + Tb[1].x * v1z + Tb[1].y;
        op[1] = Tb[2].x * v1x + Tb[2].y * v1y + Tb[3].x * v1z + Tb[3].y;
        op[2] = Tb[4].x * v1x + Tb[4].y * v1y + Tb[5].x * v1z + Tb[5].y;
    }
}

extern "C" void kernel_launch(void* const* d_in, const int* in_sizes, int n_in,
                              void* d_out, int out_size, void* d_ws, size_t ws_size,
                              hipStream_t stream) {
    const float* V    = (const float*)d_in[0];
    const float* J    = (const float*)d_in[1];
    const float* pose = (const float*)d_in[2];
    const float* W    = (const float*)d_in[3];
    float* out = (float*)d_out;
    float* Gc  = (float*)d_ws;  // NB*288 floats = 147456 B

    chain_kernel<<<NB, 64, 0, stream>>>(J, pose, Gc);
    dim3 grid((NV + 511) / 512, NB);
    lbs_kernel<<<grid, 256, 0, stream>>>(V, W, Gc, out);
}

// Round 8
// 26.933 us; speedup vs baseline: 1.4172x; 1.4172x over previous
//
#include <hip/hip_runtime.h>
#include <math.h>

#define NJ 24
#define NV 6890
#define NB 128

// Ancestor chains (closest ancestor first), -1 padded. Max depth 8.
__constant__ int d_anc[NJ][8] = {
  {-1,-1,-1,-1,-1,-1,-1,-1},
  { 0,-1,-1,-1,-1,-1,-1,-1},
  { 0,-1,-1,-1,-1,-1,-1,-1},
  { 0,-1,-1,-1,-1,-1,-1,-1},
  { 1, 0,-1,-1,-1,-1,-1,-1},
  { 2, 0,-1,-1,-1,-1,-1,-1},
  { 3, 0,-1,-1,-1,-1,-1,-1},
  { 4, 1, 0,-1,-1,-1,-1,-1},
  { 5, 2, 0,-1,-1,-1,-1,-1},
  { 6, 3, 0,-1,-1,-1,-1,-1},
  { 7, 4, 1, 0,-1,-1,-1,-1},
  { 8, 5, 2, 0,-1,-1,-1,-1},
  { 9, 6, 3, 0,-1,-1,-1,-1},
  { 9, 6, 3, 0,-1,-1,-1,-1},
  { 9, 6, 3, 0,-1,-1,-1,-1},
  {12, 9, 6, 3, 0,-1,-1,-1},
  {13, 9, 6, 3, 0,-1,-1,-1},
  {14, 9, 6, 3, 0,-1,-1,-1},
  {16,13, 9, 6, 3, 0,-1,-1},
  {17,14, 9, 6, 3, 0,-1,-1},
  {18,16,13, 9, 6, 3, 0,-1},
  {19,17,14, 9, 6, 3, 0,-1},
  {20,18,16,13, 9, 6, 3, 0},
  {21,19,17,14, 9, 6, 3, 0}
};
__constant__ int d_par[NJ] = {-1,0,0,0,1,2,3,4,5,6,7,8,9,9,9,12,13,14,16,17,18,19,20,21};

// Kernel 1: per-batch Rodrigues + parallel ancestor-path chain + J-correction.
// Output layout TRANSPOSED: Gc_t[b][j][m], j=r*4+c (12 rows), m contiguous
// (24). {Gc_t[j][m], Gc_t[j][m+1]} is an aligned SGPR pair for pk_fma.
__global__ __launch_bounds__(64) void chain_kernel(const float* __restrict__ J,
                                                   const float* __restrict__ pose,
                                                   float* __restrict__ Gc) {
    int b = blockIdx.x;
    int tid = threadIdx.x;
    __shared__ float A[NJ][12];   // local [R|t] per joint

    if (tid < NJ) {
        int i = tid;
        const float* p = pose + ((size_t)b * NJ + i) * 3;
        float rx = p[0], ry = p[1], rz = p[2];
        float ex = rx + 1e-8f, ey = ry + 1e-8f, ez = rz + 1e-8f;
        float theta = sqrtf(ex * ex + ey * ey + ez * ez);
        float inv = 1.0f / theta;
        float hx = rx * inv, hy = ry * inv, hz = rz * inv;
        float c = cosf(theta * (float)M_PI);
        float s = sinf(theta);
        float oc = 1.0f - c;
        const float* jp = J + ((size_t)b * NJ + i) * 3;
        int par = d_par[i];
        float tx, ty, tz;
        if (par < 0) {
            tx = jp[0]; ty = jp[1]; tz = jp[2];
        } else {
            const float* jq = J + ((size_t)b * NJ + par) * 3;
            tx = jp[0] - jq[0]; ty = jp[1] - jq[1]; tz = jp[2] - jq[2];
        }
        A[i][0]  = c + oc * hx * hx;
        A[i][1]  = oc * hx * hy - s * hz;
        A[i][2]  = oc * hx * hz + s * hy;
        A[i][3]  = tx;
        A[i][4]  = oc * hy * hx + s * hz;
        A[i][5]  = c + oc * hy * hy;
        A[i][6]  = oc * hy * hz - s * hx;
        A[i][7]  = ty;
        A[i][8]  = oc * hz * hx - s * hy;
        A[i][9]  = oc * hz * hy + s * hx;
        A[i][10] = c + oc * hz * hz;
        A[i][11] = tz;
    }
    __syncthreads();

    if (tid < NJ) {
        int i = tid;
        float M[12];
        #pragma unroll
        for (int j = 0; j < 12; j++) M[j] = A[i][j];

        for (int k = 0; k < 8; k++) {
            int p = d_anc[i][k];
            if (p < 0) break;
            float P[12];
            #pragma unroll
            for (int j = 0; j < 12; j++) P[j] = A[p][j];
            float N[12];
            #pragma unroll
            for (int r = 0; r < 3; r++) {
                float p0 = P[r*4+0], p1 = P[r*4+1], p2 = P[r*4+2], p3 = P[r*4+3];
                N[r*4+0] = p0 * M[0] + p1 * M[4] + p2 * M[8];
                N[r*4+1] = p0 * M[1] + p1 * M[5] + p2 * M[9];
                N[r*4+2] = p0 * M[2] + p1 * M[6] + p2 * M[10];
                N[r*4+3] = p0 * M[3] + p1 * M[7] + p2 * M[11] + p3;
            }
            #pragma unroll
            for (int j = 0; j < 12; j++) M[j] = N[j];
        }

        const float* jp = J + ((size_t)b * NJ + i) * 3;
        float jx = jp[0], jy = jp[1], jz = jp[2];
        float* o = Gc + (size_t)b * 288;   // [12][24]
        #pragma unroll
        for (int r = 0; r < 3; r++) {
            float g0 = M[r*4+0], g1 = M[r*4+1], g2 = M[r*4+2], g3 = M[r*4+3];
            float corr = g0 * jx + g1 * jy + g2 * jz;
            o[(r*4+0)*24 + i] = g0;
            o[(r*4+1)*24 + i] = g1;
            o[(r*4+2)*24 + i] = g2;
            o[(r*4+3)*24 + i] = g3 - corr;
        }
    }
}

typedef __attribute__((ext_vector_type(16))) float fx16;
typedef __attribute__((ext_vector_type(2)))  float f2;

__device__ __forceinline__ f2 mkf2(float a, float b) { f2 r; r.x = a; r.y = b; return r; }

// e is a compile-time constant after unrolling; &15 keeps dead arms in range.
#define GPAIR(e) ((e) < 16 ? mkf2(gA[(e) & 15], gA[((e) + 1) & 15]) \
                : (e) < 32 ? mkf2(gB[((e) - 16) & 15], gB[((e) - 15) & 15]) \
                           : mkf2(gC[((e) - 32) & 15], gC[((e) - 31) & 15]))

// Kernel 2: per-vertex skinning. Identical per-vertex body to the best (R6)
// version: 18x s_load_dwordx16 SMEM Gc, v_pk_fma_f32 blend. Each thread now
// processes TWO vertices SEQUENTIALLY (unroll 1): registers fully reused, so
// VGPR stays at the 1-vert level while wave count halves (13824 -> 6912) and
// per-wave fixed costs (block start, SMEM cold miss) amortize over 2 verts.
__global__ __launch_bounds__(256) void lbs_kernel(const float* __restrict__ V,
                                                  const float* __restrict__ W,
                                                  const float* __restrict__ Gc,
                                                  float* __restrict__ out) {
    const int b = blockIdx.y;
    const int tid = threadIdx.x;
    const int nbase = blockIdx.x * 512 + tid;
    if (nbase >= NV) return;

    const float* gb = Gc + (size_t)b * 288;

    #pragma unroll 1
    for (int v = 0; v < 2; v++) {
        const int n = nbase + v * 256;
        if (n >= NV) break;

        const float4* wp = (const float4*)(W + ((size_t)b * NV + n) * 24);
        float4 w4[6];
        #pragma unroll
        for (int k = 0; k < 6; k++) w4[k] = wp[k];
        f2 wpr[12];
        #pragma unroll
        for (int k = 0; k < 6; k++) {
            wpr[2 * k + 0] = mkf2(w4[k].x, w4[k].y);
            wpr[2 * k + 1] = mkf2(w4[k].z, w4[k].w);
        }

        f2 T2[12];
        #pragma unroll
        for (int j = 0; j < 12; j++) T2[j] = mkf2(0.0f, 0.0f);

        #pragma unroll
        for (int c = 0; c < 6; c++) {
            // rows j=2c (offsets 0..23) and j=2c+1 (offsets 24..47) of Gc_t[b]
            fx16 gA, gB, gC;
            const float* p = gb + c * 48;
            asm volatile("s_load_dwordx16 %0, %3, 0x0\n\t"
                         "s_load_dwordx16 %1, %3, 0x40\n\t"
                         "s_load_dwordx16 %2, %3, 0x80\n\t"
                         "s_waitcnt lgkmcnt(0)"
                         : "=&s"(gA), "=&s"(gB), "=&s"(gC)
                         : "s"(p));

            f2 TA = T2[2 * c + 0];
            f2 TB = T2[2 * c + 1];
            #pragma unroll
            for (int q = 0; q < 12; q++) {
                f2 gpA = GPAIR(2 * q);
                f2 gpB = GPAIR(24 + 2 * q);
                asm("v_pk_fma_f32 %0, %1, %2, %0" : "+v"(TA) : "v"(wpr[q]), "s"(gpA));
                asm("v_pk_fma_f32 %0, %1, %2, %0" : "+v"(TB) : "v"(wpr[q]), "s"(gpB));
            }
            T2[2 * c + 0] = TA;
            T2[2 * c + 1] = TB;
        }

        float T[12];
        #pragma unroll
        for (int j = 0; j < 12; j++) T[j] = T2[j].x + T2[j].y;

        const float* vp = V + ((size_t)b * NV + n) * 3;
        float vx = vp[0], vy = vp[1], vz = vp[2];
        float* op = out + ((size_t)b * NV + n) * 3;
        op[0] = T[0] * vx + T[1] * vy + T[2]  * vz + T[3];
        op[1] = T[4] * vx + T[5] * vy + T[6]  * vz + T[7];
        op[2] = T[8] * vx + T[9] * vy + T[10] * vz + T[11];
    }
}

extern "C" void kernel_launch(void* const* d_in, const int* in_sizes, int n_in,
                              void* d_out, int out_size, void* d_ws, size_t ws_size,
                              hipStream_t stream) {
    const float* V    = (const float*)d_in[0];
    const float* J    = (const float*)d_in[1];
    const float* pose = (const float*)d_in[2];
    const float* W    = (const float*)d_in[3];
    float* out = (float*)d_out;
    float* Gc  = (float*)d_ws;  // NB*288 floats = 147456 B

    chain_kernel<<<NB, 64, 0, stream>>>(J, pose, Gc);
    dim3 grid((NV + 511) / 512, NB);
    lbs_kernel<<<grid, 256, 0, stream>>>(V, W, Gc, out);
}